// Round 5
// baseline (385.851 us; speedup 1.0000x reference)
//
#include <hip/hip_runtime.h>

#define N_ATOMS 30000
#define NJ 12
#define FDIM 128

typedef __attribute__((ext_vector_type(8))) short short8;
typedef __attribute__((ext_vector_type(4))) float f32x4;

// ws layout (bytes)
#define WFRAG_OFF 0          // 8 mats * 32768 B  (bf16 frag-linear)
#define GFRAG_OFF 262144     // 3 mats * 8192  B
#define MFRAG_OFF 286720     // 2 mats * 32768 B
#define FEA_OFF   483328     // 3 * 30000*128 bf16 (s,p,d fea)
#define FEA_ELEMS 3840000
#define CFEA_OFF  23523328   // 30000*128 f32 (final_c)

__device__ __forceinline__ unsigned short f2b(float f){
  unsigned u = __builtin_bit_cast(unsigned, f);
  u = (u + 0x7fffu + ((u >> 16) & 1u)) >> 16;
  return (unsigned short)u;
}
__device__ __forceinline__ float b2f(unsigned short s){
  unsigned u = ((unsigned)s) << 16;
  return __builtin_bit_cast(float, u);
}
__device__ __forceinline__ unsigned pack_bf2(float a, float b){
  unsigned ua = __builtin_bit_cast(unsigned, a);
  unsigned ub = __builtin_bit_cast(unsigned, b);
  ua = (ua + 0x7fffu + ((ua >> 16) & 1u)) >> 16;
  ub = (ub + 0x7fffu + ((ub >> 16) & 1u)) & 0xffff0000u;
  return ua | ub;
}
__device__ __forceinline__ float silu_f(float x){ return x / (1.0f + __expf(-x)); }
__device__ __forceinline__ void lds_fence(){
  __builtin_amdgcn_sched_barrier(0);
  asm volatile("s_waitcnt lgkmcnt(0)" ::: "memory");
  __builtin_amdgcn_sched_barrier(0);
}
__device__ __forceinline__ short8 frag4(unsigned d0, unsigned d1, unsigned d2, unsigned d3, bool valid){
  if (!valid){ d0 = 0u; d1 = 0u; d2 = 0u; d3 = 0u; }
  uint4 u; u.x = d0; u.y = d1; u.z = d2; u.w = d3;
  return __builtin_bit_cast(short8, u);
}

struct Ptr8 { const float* p[8]; };
struct Ptr3 { const float* p[3]; };
struct Bias { const float* br[4]; const float* b1[4]; };

// ---------------- kernel 0: M=P1*P2^T / D1*D2^T (direct frag), W/G frag pack ---
__global__ __launch_bounds__(256) void k_prep(
    const float* __restrict__ P1, const float* __restrict__ P2,
    const float* __restrict__ D1, const float* __restrict__ D2,
    Ptr8 w8, Ptr3 g3, char* __restrict__ ws)
{
  int b = blockIdx.x, t = threadIdx.x;
  if (b < 16){
    int mat = b >> 3, rb = b & 7;
    const float* A = mat ? D1 : P1;
    const float* B = mat ? D2 : P2;
    unsigned short* dst = (unsigned short*)(ws + MFRAG_OFF) + (size_t)mat*16384;
    for (int it = 0; it < 8; ++it){
      int o = it*256 + t;
      int row = rb*16 + (o >> 7), col = o & 127;   // row = k, col = f'
      const float4* ar = (const float4*)(A + (size_t)row*128);
      const float4* br = (const float4*)(B + (size_t)col*128);
      float s = 0.f;
      #pragma unroll 8
      for (int q = 0; q < 32; ++q){
        float4 a = ar[q], c = br[q];
        s += a.x*c.x + a.y*c.y + a.z*c.z + a.w*c.w;
      }
      int ks = row >> 5, ft = col >> 4;
      int ln = (col & 15) | (((row >> 3) & 3) << 4);
      dst[(size_t)(((ks*8 + ft)*64 + ln)*8 + (row & 7))] = f2b(s);
    }
  } else if (b < 24){
    int mat = b - 16;
    const float* W = w8.p[mat];
    unsigned short* dst = (unsigned short*)(ws + WFRAG_OFF) + (size_t)mat*16384;
    for (int it = 0; it < 64; ++it){
      int idx = it*256 + t;
      int i = idx & 7, ln = (idx >> 3) & 63, ft = (idx >> 9) & 7, ks = idx >> 12;
      int f = ft*16 + (ln & 15);
      int k = ks*32 + ((ln >> 4) & 3)*8 + i;
      dst[idx] = f2b(W[(size_t)f*128 + k]);
    }
  } else {
    int mat = b - 24;
    const float* G = g3.p[mat];
    unsigned short* dst = (unsigned short*)(ws + GFRAG_OFF) + (size_t)mat*4096;
    for (int it = 0; it < 16; ++it){
      int idx = it*256 + t;
      int i = idx & 7, ln = (idx >> 3) & 63, ft = idx >> 9;
      int f = ft*16 + (ln & 15);
      int k = ((ln >> 4) & 3)*8 + i;
      dst[idx] = f2b(G[(size_t)f*32 + k]);
    }
  }
}

// ---------------- kernel 1: ResMLP, one channel per block.y --------------------
__global__ __launch_bounds__(256, 4) void k_resmlp(
    const float* __restrict__ x, char* __restrict__ ws, Bias bs)
{
  __shared__ alignas(16) char sm[32768];
  const int tid = threadIdx.x, lane = tid & 63;
  const int wid = __builtin_amdgcn_readfirstlane(tid >> 6);
  const int lo = lane & 15, hi = lane >> 4;
  const int ch = blockIdx.y;
  const int rowbase = (int)blockIdx.x*64 + wid*16;
  char* xL = sm + wid*8192;
  char* hL = xL + 4096;

  #pragma unroll
  for (int it = 0; it < 8; ++it){
    int e4 = it*64 + lane;
    int row = e4 >> 5, k0 = (e4 & 31)*4;
    int grow = rowbase + row; if (grow >= N_ATOMS) grow = N_ATOMS-1;
    float4 v = *(const float4*)(x + (size_t)grow*FDIM + k0);
    uint2 u;
    u.x = pack_bf2(silu_f(v.x), silu_f(v.y));
    u.y = pack_bf2(silu_f(v.z), silu_f(v.w));
    int ks = k0 >> 5, h2 = (k0 >> 3) & 3, i0 = k0 & 7, lanep = row | (h2 << 4);
    *(uint2*)(xL + ks*1024 + lanep*16 + i0*2) = u;
  }
  lds_fence();
  short8 A[4];
  #pragma unroll
  for (int ks = 0; ks < 4; ++ks) A[ks] = *(const short8*)(xL + ks*1024 + lane*16);

  const char* wrp = ws + (size_t)(ch*2)*32768;
  const char* w1p = ws + (size_t)(ch*2 + 1)*32768;
  const float* brp = bs.br[ch];
  const float* b1p = bs.b1[ch];

  f32x4 acc[8];
  #pragma unroll
  for (int ft = 0; ft < 8; ++ft) acc[ft] = (f32x4){0.f,0.f,0.f,0.f};
  #pragma unroll
  for (int ks = 0; ks < 4; ++ks){
    #pragma unroll
    for (int ft = 0; ft < 8; ++ft){
      short8 B = *(const short8*)(wrp + (size_t)(((ks*8 + ft)*64 + lane)*16));
      acc[ft] = __builtin_amdgcn_mfma_f32_16x16x32_bf16(A[ks], B, acc[ft], 0, 0, 0);
    }
  }
  #pragma unroll
  for (int ft = 0; ft < 8; ++ft){
    int f = ft*16 + lo;
    float bias = brp[f];
    #pragma unroll
    for (int r = 0; r < 4; ++r){
      int grow = rowbase + hi*4 + r; if (grow >= N_ATOMS) grow = N_ATOMS-1;
      float h = acc[ft][r] + x[(size_t)grow*FDIM + f] + bias;
      float sh = silu_f(h);
      int ks2 = f >> 5, h2 = (f >> 3) & 3, i2 = f & 7, lanep = (hi*4 + r) | (h2 << 4);
      *(unsigned short*)(hL + ks2*1024 + lanep*16 + i2*2) = f2b(sh);
    }
  }
  lds_fence();
  short8 A2[4];
  #pragma unroll
  for (int ks = 0; ks < 4; ++ks) A2[ks] = *(const short8*)(hL + ks*1024 + lane*16);

  f32x4 acc2[8];
  #pragma unroll
  for (int ft = 0; ft < 8; ++ft) acc2[ft] = (f32x4){0.f,0.f,0.f,0.f};
  #pragma unroll
  for (int ks = 0; ks < 4; ++ks){
    #pragma unroll
    for (int ft = 0; ft < 8; ++ft){
      short8 B = *(const short8*)(w1p + (size_t)(((ks*8 + ft)*64 + lane)*16));
      acc2[ft] = __builtin_amdgcn_mfma_f32_16x16x32_bf16(A2[ks], B, acc2[ft], 0, 0, 0);
    }
  }
  if (ch == 0){
    float* cfea = (float*)(ws + CFEA_OFF);
    #pragma unroll
    for (int ft = 0; ft < 8; ++ft){
      int f = ft*16 + lo;
      float bb = b1p[f];
      #pragma unroll
      for (int r = 0; r < 4; ++r){
        int grow = rowbase + hi*4 + r; if (grow >= N_ATOMS) grow = N_ATOMS-1;
        cfea[(size_t)grow*FDIM + f] = acc2[ft][r] + bb;
      }
    }
  } else {
    unsigned short* fea = (unsigned short*)(ws + FEA_OFF) + (size_t)(ch-1)*FEA_ELEMS;
    #pragma unroll
    for (int ft = 0; ft < 8; ++ft){
      int f = ft*16 + lo;
      float bb = b1p[f];
      #pragma unroll
      for (int r = 0; r < 4; ++r){
        int grow = rowbase + hi*4 + r; if (grow >= N_ATOMS) grow = N_ATOMS-1;
        fea[(size_t)grow*FDIM + f] = f2b(acc2[ft][r] + bb);
      }
    }
  }
}

// ---------------- kernel 2 helpers ---------------------------------------------
// batched quadratic pass over one 16-row tile of accB; writes per-row sums to rs
__device__ __forceinline__ void quad_pass(const char* __restrict__ mb,
    const char* accB, float* rs, int rowbase, int nvalid, int rsbase,
    int lane, int lo, int hi)
{
  short8 Aq[4];
  #pragma unroll
  for (int ks = 0; ks < 4; ++ks){
    short8 a8 = (short8){0,0,0,0,0,0,0,0};
    if (lo < nvalid) a8 = *(const short8*)(accB + (rowbase + lo)*272 + ks*64 + hi*16);
    Aq[ks] = a8;
  }
  f32x4 acc2[8];
  #pragma unroll
  for (int ft = 0; ft < 8; ++ft) acc2[ft] = (f32x4){0.f,0.f,0.f,0.f};
  #pragma unroll
  for (int ks = 0; ks < 4; ++ks){
    #pragma unroll
    for (int ft = 0; ft < 8; ++ft){
      short8 B = *(const short8*)(mb + (size_t)(((ks*8 + ft)*64 + lane)*16));
      acc2[ft] = __builtin_amdgcn_mfma_f32_16x16x32_bf16(Aq[ks], B, acc2[ft], 0, 0, 0);
    }
  }
  float part[4] = {0.f, 0.f, 0.f, 0.f};
  #pragma unroll
  for (int ft = 0; ft < 8; ++ft){
    #pragma unroll
    for (int r = 0; r < 4; ++r){
      int row = hi*4 + r;
      if (row < nvalid)
        part[r] += acc2[ft][r] * b2f(*(const unsigned short*)(accB + (rowbase + row)*272 + ft*32 + lo*2));
    }
  }
  #pragma unroll
  for (int r = 0; r < 4; ++r){
    #pragma unroll
    for (int m = 1; m < 16; m <<= 1) part[r] += __shfl_xor(part[r], m);
  }
  if (lo == 0){
    #pragma unroll
    for (int r = 0; r < 4; ++r){
      int row = hi*4 + r;
      if (row < nvalid) rs[rsbase + row] = part[r];
    }
  }
}

// ---------------- kernel 2: 4 atoms/wave, channel-major, batched quads ---------
__global__ __launch_bounds__(256, 4) void k_main(
    const float* __restrict__ gs, const float* __restrict__ gp,
    const float* __restrict__ gd, const int* __restrict__ nbr,
    char* __restrict__ ws, float* __restrict__ out)
{
  __shared__ alignas(16) char sm[4*9216];
  const int tid = threadIdx.x, lane = tid & 63;
  const int wid = __builtin_amdgcn_readfirstlane(tid >> 6);
  const int lo = lane & 15, hi = lane >> 4;
  const bool jvalid = lo < NJ;
  const int jc = jvalid ? lo : NJ-1;
  char* accB = sm + wid*9216;              // 32 rows * 272 B bf16
  float* rs  = (float*)(accB + 8704);      // rs[36]: p rows 0-15, d rows 16-35
  const char* gfrag = ws + GFRAG_OFF;
  const char* mfrag = ws + MFRAG_OFF;
  const unsigned short* feaS = (const unsigned short*)(ws + FEA_OFF);
  const unsigned short* feaP = feaS + FEA_ELEMS;
  const unsigned short* feaD = feaS + 2*FEA_ELEMS;
  const float* cfea = (const float*)(ws + CFEA_OFF);
  const f32x4 z4 = {0.f,0.f,0.f,0.f};

  const int au0 = ((int)blockIdx.x*4 + wid)*4;

  int nbrv = 0;
  if (lane < 4*NJ) nbrv = nbr[(size_t)au0*NJ + lane];

  float outv0[4] = {0.f,0.f,0.f,0.f};
  float outv1[4] = {0.f,0.f,0.f,0.f};

#define LOADW(W, FEA, M) do { \
    int njr_[4]; \
    _Pragma("unroll") for (int r = 0; r < 4; ++r){ \
      int j_ = hi*4 + r; if (j_ > NJ-1) j_ = NJ-1; \
      njr_[r] = __shfl(nbrv, (M)*NJ + j_); } \
    _Pragma("unroll") for (int ft = 0; ft < 8; ++ft) \
      _Pragma("unroll") for (int r = 0; r < 4; ++r) \
        W[ft][r] = (FEA)[(size_t)njr_[r]*FDIM + ft*16 + lo]; \
  } while(0)

  // ---------- s channel: weighted j-sum -> outv ----------
  {
    short8 Bg[8];
    #pragma unroll
    for (int ft = 0; ft < 8; ++ft)
      Bg[ft] = *(const short8*)(gfrag + (size_t)((ft*64 + lane)*16));
    #pragma unroll
    for (int m = 0; m < 4; ++m){
      const float* gsp = gs + (size_t)(au0+m)*384 + (jc*32 + hi*8);
      f32x4 v0 = *(const f32x4*)(gsp);
      f32x4 v1 = *(const f32x4*)(gsp + 4);
      short8 AfS = frag4(pack_bf2(v0[0],v0[1]), pack_bf2(v0[2],v0[3]),
                         pack_bf2(v1[0],v1[1]), pack_bf2(v1[2],v1[3]), jvalid);
      unsigned short w[8][4];
      LOADW(w, feaS, m);
      #pragma unroll
      for (int ft = 0; ft < 8; ++ft){
        float w0 = b2f(w[ft][0]), w1 = b2f(w[ft][1]), w2 = b2f(w[ft][2]), w3 = b2f(w[ft][3]);
        f32x4 c = __builtin_amdgcn_mfma_f32_16x16x32_bf16(AfS, Bg[ft], z4, 0, 0, 0);
        float p = c[0]*w0 + c[1]*w1 + c[2]*w2 + c[3]*w3;
        p += __shfl_xor(p, 16);
        p += __shfl_xor(p, 32);
        if (ft == hi)     outv0[m] += p;
        if (ft == hi + 4) outv1[m] += p;
      }
    }
  }

  // ---------- p channel: j-sum -> accB rows 0..11 ----------
  {
    short8 Bg[8];
    #pragma unroll
    for (int ft = 0; ft < 8; ++ft)
      Bg[ft] = *(const short8*)(gfrag + 8192 + (size_t)((ft*64 + lane)*16));
    #pragma unroll
    for (int m = 0; m < 4; ++m){
      const float* gpp = gp + (size_t)(au0+m)*1152 + (jc*96 + hi*24);
      float pr[24];
      #pragma unroll
      for (int q = 0; q < 6; ++q){
        f32x4 v = *(const f32x4*)(gpp + q*4);
        #pragma unroll
        for (int c2 = 0; c2 < 4; ++c2) pr[q*4+c2] = v[c2];
      }
      short8 AfP[3];
      #pragma unroll
      for (int a = 0; a < 3; ++a)
        AfP[a] = frag4(pack_bf2(pr[0+a],pr[3+a]),  pack_bf2(pr[6+a],pr[9+a]),
                       pack_bf2(pr[12+a],pr[15+a]), pack_bf2(pr[18+a],pr[21+a]), jvalid);
      unsigned short w[8][4];
      LOADW(w, feaP, m);
      #pragma unroll
      for (int ft = 0; ft < 8; ++ft){
        float w0 = b2f(w[ft][0]), w1 = b2f(w[ft][1]), w2 = b2f(w[ft][2]), w3 = b2f(w[ft][3]);
        #pragma unroll
        for (int a = 0; a < 3; ++a){
          f32x4 c = __builtin_amdgcn_mfma_f32_16x16x32_bf16(AfP[a], Bg[ft], z4, 0, 0, 0);
          float p = c[0]*w0 + c[1]*w1 + c[2]*w2 + c[3]*w3;
          p += __shfl_xor(p, 16);
          p += __shfl_xor(p, 32);
          if (lane < 16) *(unsigned short*)(accB + (m*3+a)*272 + ft*32 + lane*2) = f2b(p);
        }
      }
    }
  }

  // ---------- d channel: j-sum -> accB rows 12..31 ----------
  {
    short8 Bg[8];
    #pragma unroll
    for (int ft = 0; ft < 8; ++ft)
      Bg[ft] = *(const short8*)(gfrag + 16384 + (size_t)((ft*64 + lane)*16));
    #pragma unroll
    for (int m = 0; m < 4; ++m){
      const float* gdp = gd + (size_t)(au0+m)*1920 + (jc*160 + hi*40);
      float dr[40];
      #pragma unroll
      for (int q = 0; q < 10; ++q){
        f32x4 v = *(const f32x4*)(gdp + q*4);
        #pragma unroll
        for (int c2 = 0; c2 < 4; ++c2) dr[q*4+c2] = v[c2];
      }
      short8 AfD[5];
      #pragma unroll
      for (int a = 0; a < 5; ++a)
        AfD[a] = frag4(pack_bf2(dr[0+a],dr[5+a]),   pack_bf2(dr[10+a],dr[15+a]),
                       pack_bf2(dr[20+a],dr[25+a]), pack_bf2(dr[30+a],dr[35+a]), jvalid);
      unsigned short w[8][4];
      LOADW(w, feaD, m);
      #pragma unroll
      for (int ft = 0; ft < 8; ++ft){
        float w0 = b2f(w[ft][0]), w1 = b2f(w[ft][1]), w2 = b2f(w[ft][2]), w3 = b2f(w[ft][3]);
        #pragma unroll
        for (int a = 0; a < 5; ++a){
          f32x4 c = __builtin_amdgcn_mfma_f32_16x16x32_bf16(AfD[a], Bg[ft], z4, 0, 0, 0);
          float p = c[0]*w0 + c[1]*w1 + c[2]*w2 + c[3]*w3;
          p += __shfl_xor(p, 16);
          p += __shfl_xor(p, 32);
          if (lane < 16) *(unsigned short*)(accB + (12 + m*5+a)*272 + ft*32 + lane*2) = f2b(p);
        }
      }
    }
  }

  lds_fence();   // accB rows visible wave-wide

  // ---------- batched quadratic heads ----------
  quad_pass(mfrag,         accB, rs,  0, 12,  0, lane, lo, hi);   // p: 4 atoms x 3
  quad_pass(mfrag + 32768, accB, rs, 12, 15, 16, lane, lo, hi);   // d: atoms 0-2
  quad_pass(mfrag + 32768, accB, rs, 27,  5, 31, lane, lo, hi);   // d: atom 3

  lds_fence();   // rs visible

  // ---------- finalize ----------
  #pragma unroll
  for (int m = 0; m < 4; ++m){
    float qp = rs[3*m] + rs[3*m+1] + rs[3*m+2];
    float qd = rs[16+5*m] + rs[16+5*m+1] + rs[16+5*m+2] + rs[16+5*m+3] + rs[16+5*m+4];
    float add = qp + qd;
    size_t ob = (size_t)(au0+m)*FDIM;
    out[ob + lane]      = cfea[ob + lane]      + outv0[m] + add;
    out[ob + 64 + lane] = cfea[ob + 64 + lane] + outv1[m] + add;
  }
#undef LOADW
}

// ---------------- launch -------------------------------------------------------
extern "C" void kernel_launch(void* const* d_in, const int* in_sizes, int n_in,
                              void* d_out, int out_size, void* d_ws, size_t ws_size,
                              hipStream_t stream)
{
  const float* atom_fea = (const float*)d_in[0];
  const int*   nbr      = (const int*)d_in[1];
  const float* gs = (const float*)d_in[2];
  const float* gp = (const float*)d_in[3];
  const float* gd = (const float*)d_in[4];
  const float* Gs = (const float*)d_in[5];
  const float* Gp = (const float*)d_in[6];
  const float* Gd = (const float*)d_in[7];
  const float* P1 = (const float*)d_in[8];
  const float* P2 = (const float*)d_in[9];
  const float* D1 = (const float*)d_in[10];
  const float* D2 = (const float*)d_in[11];

  Ptr8 w8;
  w8.p[0] = (const float*)d_in[12];  // c_wr
  w8.p[1] = (const float*)d_in[14];  // c_w1
  w8.p[2] = (const float*)d_in[16];  // s_wr
  w8.p[3] = (const float*)d_in[18];  // s_w1
  w8.p[4] = (const float*)d_in[20];  // p_wr
  w8.p[5] = (const float*)d_in[22];  // p_w1
  w8.p[6] = (const float*)d_in[24];  // d_wr
  w8.p[7] = (const float*)d_in[26];  // d_w1
  Ptr3 g3; g3.p[0] = Gs; g3.p[1] = Gp; g3.p[2] = Gd;
  Bias bs;
  bs.br[0] = (const float*)d_in[13]; bs.b1[0] = (const float*)d_in[15];
  bs.br[1] = (const float*)d_in[17]; bs.b1[1] = (const float*)d_in[19];
  bs.br[2] = (const float*)d_in[21]; bs.b1[2] = (const float*)d_in[23];
  bs.br[3] = (const float*)d_in[25]; bs.b1[3] = (const float*)d_in[27];

  char* ws = (char*)d_ws;
  float* out = (float*)d_out;

  k_prep  <<<27, 256, 0, stream>>>(P1, P2, D1, D2, w8, g3, ws);
  dim3 g1((N_ATOMS + 63)/64, 4);
  k_resmlp<<<g1, 256, 0, stream>>>(atom_fea, ws, bs);
  k_main  <<<N_ATOMS/16, 256, 0, stream>>>(gs, gp, gd, nbr, ws, out);
}

// Round 6
// 270.075 us; speedup vs baseline: 1.4287x; 1.4287x over previous
//
#include <hip/hip_runtime.h>

#define N_ATOMS 30000
#define NJ 12
#define FDIM 128

typedef __attribute__((ext_vector_type(8))) short short8;
typedef __attribute__((ext_vector_type(4))) float f32x4;

// ws layout (bytes)
#define WFRAG_OFF 0          // 8 mats * 32768 B (bf16 frag-linear)
#define GFRAG_OFF 262144     // 3 mats * 8192 B
#define MFRAG_OFF 286720     // 2 mats * 32768 B
#define FEA_OFF   483328     // 3 * 30000*128 bf16 (s,p,d fea)
#define FEA_ELEMS 3840000
#define ALLP_OFF  23523328   // 90000 rows * 128 bf16
#define ALLD_OFF  46563328   // 150000 rows * 128 bf16
#define QP_OFF    84963328   // 90000 f32
#define QD_OFF    85323328   // 150000 f32

__device__ __forceinline__ unsigned short f2b(float f){
  unsigned u = __builtin_bit_cast(unsigned, f);
  u = (u + 0x7fffu + ((u >> 16) & 1u)) >> 16;
  return (unsigned short)u;
}
__device__ __forceinline__ float b2f(unsigned short s){
  unsigned u = ((unsigned)s) << 16;
  return __builtin_bit_cast(float, u);
}
__device__ __forceinline__ unsigned pack_bf2(float a, float b){
  unsigned ua = __builtin_bit_cast(unsigned, a);
  unsigned ub = __builtin_bit_cast(unsigned, b);
  ua = (ua + 0x7fffu + ((ua >> 16) & 1u)) >> 16;
  ub = (ub + 0x7fffu + ((ub >> 16) & 1u)) & 0xffff0000u;
  return ua | ub;
}
__device__ __forceinline__ float silu_f(float x){ return x / (1.0f + __expf(-x)); }
__device__ __forceinline__ void lds_fence(){
  __builtin_amdgcn_sched_barrier(0);
  asm volatile("s_waitcnt lgkmcnt(0)" ::: "memory");
  __builtin_amdgcn_sched_barrier(0);
}
__device__ __forceinline__ short8 frag4(unsigned d0, unsigned d1, unsigned d2, unsigned d3, bool valid){
  if (!valid){ d0 = 0u; d1 = 0u; d2 = 0u; d3 = 0u; }
  uint4 u; u.x = d0; u.y = d1; u.z = d2; u.w = d3;
  return __builtin_bit_cast(short8, u);
}

struct Ptr8 { const float* p[8]; };
struct Ptr3 { const float* p[3]; };
struct Bias { const float* br[4]; const float* b1[4]; };

// ---------------- kernel 0: M=P1*P2^T / D1*D2^T (direct frag), W/G frag pack ---
__global__ __launch_bounds__(256) void k_prep(
    const float* __restrict__ P1, const float* __restrict__ P2,
    const float* __restrict__ D1, const float* __restrict__ D2,
    Ptr8 w8, Ptr3 g3, char* __restrict__ ws)
{
  int b = blockIdx.x, t = threadIdx.x;
  if (b < 16){
    int mat = b >> 3, rb = b & 7;
    const float* A = mat ? D1 : P1;
    const float* B = mat ? D2 : P2;
    unsigned short* dst = (unsigned short*)(ws + MFRAG_OFF) + (size_t)mat*16384;
    for (int it = 0; it < 8; ++it){
      int o = it*256 + t;
      int row = rb*16 + (o >> 7), col = o & 127;   // row = k, col = f'
      const float4* ar = (const float4*)(A + (size_t)row*128);
      const float4* br = (const float4*)(B + (size_t)col*128);
      float s = 0.f;
      #pragma unroll 8
      for (int q = 0; q < 32; ++q){
        float4 a = ar[q], c = br[q];
        s += a.x*c.x + a.y*c.y + a.z*c.z + a.w*c.w;
      }
      int ks = row >> 5, ft = col >> 4;
      int ln = (col & 15) | (((row >> 3) & 3) << 4);
      dst[(size_t)(((ks*8 + ft)*64 + ln)*8 + (row & 7))] = f2b(s);
    }
  } else if (b < 24){
    int mat = b - 16;
    const float* W = w8.p[mat];
    unsigned short* dst = (unsigned short*)(ws + WFRAG_OFF) + (size_t)mat*16384;
    for (int it = 0; it < 64; ++it){
      int idx = it*256 + t;
      int i = idx & 7, ln = (idx >> 3) & 63, ft = (idx >> 9) & 7, ks = idx >> 12;
      int f = ft*16 + (ln & 15);
      int k = ks*32 + ((ln >> 4) & 3)*8 + i;
      dst[idx] = f2b(W[(size_t)f*128 + k]);
    }
  } else {
    int mat = b - 24;
    const float* G = g3.p[mat];
    unsigned short* dst = (unsigned short*)(ws + GFRAG_OFF) + (size_t)mat*4096;
    for (int it = 0; it < 16; ++it){
      int idx = it*256 + t;
      int i = idx & 7, ln = (idx >> 3) & 63, ft = idx >> 9;
      int f = ft*16 + (ln & 15);
      int k = ((ln >> 4) & 3)*8 + i;
      dst[idx] = f2b(G[(size_t)f*32 + k]);
    }
  }
}

// ---------------- kernel 1: ResMLP, one channel per block.y --------------------
__global__ __launch_bounds__(256) void k_resmlp(
    const float* __restrict__ x, char* __restrict__ ws, Bias bs,
    float* __restrict__ out)
{
  __shared__ alignas(16) char sm[32768];
  const int tid = threadIdx.x, lane = tid & 63;
  const int wid = __builtin_amdgcn_readfirstlane(tid >> 6);
  const int lo = lane & 15, hi = lane >> 4;
  const int ch = blockIdx.y;
  const int rowbase = (int)blockIdx.x*64 + wid*16;
  char* xL = sm + wid*8192;
  char* hL = xL + 4096;

  #pragma unroll
  for (int it = 0; it < 8; ++it){
    int e4 = it*64 + lane;
    int row = e4 >> 5, k0 = (e4 & 31)*4;
    int grow = rowbase + row; if (grow >= N_ATOMS) grow = N_ATOMS-1;
    float4 v = *(const float4*)(x + (size_t)grow*FDIM + k0);
    uint2 u;
    u.x = pack_bf2(silu_f(v.x), silu_f(v.y));
    u.y = pack_bf2(silu_f(v.z), silu_f(v.w));
    int ks = k0 >> 5, h2 = (k0 >> 3) & 3, i0 = k0 & 7, lanep = row | (h2 << 4);
    *(uint2*)(xL + ks*1024 + lanep*16 + i0*2) = u;
  }
  lds_fence();
  short8 A[4];
  #pragma unroll
  for (int ks = 0; ks < 4; ++ks) A[ks] = *(const short8*)(xL + ks*1024 + lane*16);

  const char* wrp = ws + (size_t)(ch*2)*32768;
  const char* w1p = ws + (size_t)(ch*2 + 1)*32768;
  const float* brp = bs.br[ch];
  const float* b1p = bs.b1[ch];

  f32x4 acc[8];
  #pragma unroll
  for (int ft = 0; ft < 8; ++ft) acc[ft] = (f32x4){0.f,0.f,0.f,0.f};
  #pragma unroll
  for (int ks = 0; ks < 4; ++ks){
    #pragma unroll
    for (int ft = 0; ft < 8; ++ft){
      short8 B = *(const short8*)(wrp + (size_t)(((ks*8 + ft)*64 + lane)*16));
      acc[ft] = __builtin_amdgcn_mfma_f32_16x16x32_bf16(A[ks], B, acc[ft], 0, 0, 0);
    }
  }
  #pragma unroll
  for (int ft = 0; ft < 8; ++ft){
    int f = ft*16 + lo;
    float bias = brp[f];
    #pragma unroll
    for (int r = 0; r < 4; ++r){
      int grow = rowbase + hi*4 + r; if (grow >= N_ATOMS) grow = N_ATOMS-1;
      float h = acc[ft][r] + x[(size_t)grow*FDIM + f] + bias;
      float sh = silu_f(h);
      int ks2 = f >> 5, h2 = (f >> 3) & 3, i2 = f & 7, lanep = (hi*4 + r) | (h2 << 4);
      *(unsigned short*)(hL + ks2*1024 + lanep*16 + i2*2) = f2b(sh);
    }
  }
  lds_fence();
  short8 A2[4];
  #pragma unroll
  for (int ks = 0; ks < 4; ++ks) A2[ks] = *(const short8*)(hL + ks*1024 + lane*16);

  f32x4 acc2[8];
  #pragma unroll
  for (int ft = 0; ft < 8; ++ft) acc2[ft] = (f32x4){0.f,0.f,0.f,0.f};
  #pragma unroll
  for (int ks = 0; ks < 4; ++ks){
    #pragma unroll
    for (int ft = 0; ft < 8; ++ft){
      short8 B = *(const short8*)(w1p + (size_t)(((ks*8 + ft)*64 + lane)*16));
      acc2[ft] = __builtin_amdgcn_mfma_f32_16x16x32_bf16(A2[ks], B, acc2[ft], 0, 0, 0);
    }
  }
  if (ch == 0){
    #pragma unroll
    for (int ft = 0; ft < 8; ++ft){
      int f = ft*16 + lo;
      float bb = b1p[f];
      #pragma unroll
      for (int r = 0; r < 4; ++r){
        int grow = rowbase + hi*4 + r; if (grow >= N_ATOMS) grow = N_ATOMS-1;
        out[(size_t)grow*FDIM + f] = acc2[ft][r] + bb;   // dup tail rows: identical
      }
    }
  } else {
    unsigned short* fea = (unsigned short*)(ws + FEA_OFF) + (size_t)(ch-1)*FEA_ELEMS;
    #pragma unroll
    for (int ft = 0; ft < 8; ++ft){
      int f = ft*16 + lo;
      float bb = b1p[f];
      #pragma unroll
      for (int r = 0; r < 4; ++r){
        int grow = rowbase + hi*4 + r; if (grow >= N_ATOMS) grow = N_ATOMS-1;
        fea[(size_t)grow*FDIM + f] = f2b(acc2[ft][r] + bb);
      }
    }
  }
}

// ---------------- channel kernel helpers ---------------------------------------
#define FPAD 288   // fea row pitch in LDS: 72 words -> hi-groups on disjoint banks

__device__ __forceinline__ void stage_fea(char* buf, const unsigned short* fea,
                                          int nb, int lane)
{
  #pragma unroll
  for (int j = 0; j < NJ; ++j){
    int nj = __shfl(nb, j);
    unsigned v = *(const unsigned*)(fea + (size_t)nj*FDIM + lane*2);
    *(unsigned*)(buf + j*FPAD + lane*4) = v;
  }
}

// ---------------- kernel s: env + weighted j-sum -> out (accumulate) -----------
__global__ __launch_bounds__(256) void k_s(
    const float* __restrict__ gs, const int* __restrict__ nbr,
    char* __restrict__ ws, float* __restrict__ out)
{
  __shared__ alignas(16) char sm[4*(NJ*FPAD)];
  const int tid = threadIdx.x, lane = tid & 63;
  const int wid = __builtin_amdgcn_readfirstlane(tid >> 6);
  const int lo = lane & 15, hi = lane >> 4;
  const bool jvalid = lo < NJ;
  const int jc = jvalid ? lo : NJ-1;
  char* feaL = sm + wid*(NJ*FPAD);
  const unsigned short* feaS = (const unsigned short*)(ws + FEA_OFF);
  const f32x4 z4 = {0.f,0.f,0.f,0.f};

  const int atom = (int)blockIdx.x*4 + wid;
  int nb = 0;
  if (lane < NJ) nb = nbr[(size_t)atom*NJ + lane];

  const float* gsp = gs + (size_t)atom*384 + (jc*32 + hi*8);
  f32x4 v0 = *(const f32x4*)(gsp);
  f32x4 v1 = *(const f32x4*)(gsp + 4);

  stage_fea(feaL, feaS, nb, lane);

  short8 AfS = frag4(pack_bf2(v0[0],v0[1]), pack_bf2(v0[2],v0[3]),
                     pack_bf2(v1[0],v1[1]), pack_bf2(v1[2],v1[3]), jvalid);
  short8 Bg[8];
  #pragma unroll
  for (int ft = 0; ft < 8; ++ft)
    Bg[ft] = *(const short8*)(ws + GFRAG_OFF + (size_t)((ft*64 + lane)*16));

  int rowoff[4];
  #pragma unroll
  for (int r = 0; r < 4; ++r){
    int j = hi*4 + r; if (j > NJ-1) j = NJ-1;
    rowoff[r] = j*FPAD;
  }

  lds_fence();
  float outv0 = 0.f, outv1 = 0.f;
  #pragma unroll
  for (int ft = 0; ft < 8; ++ft){
    int fo = (ft*16 + lo)*2;
    float w0 = b2f(*(const unsigned short*)(feaL + rowoff[0] + fo));
    float w1 = b2f(*(const unsigned short*)(feaL + rowoff[1] + fo));
    float w2 = b2f(*(const unsigned short*)(feaL + rowoff[2] + fo));
    float w3 = b2f(*(const unsigned short*)(feaL + rowoff[3] + fo));
    f32x4 c = __builtin_amdgcn_mfma_f32_16x16x32_bf16(AfS, Bg[ft], z4, 0, 0, 0);
    float p = c[0]*w0 + c[1]*w1 + c[2]*w2 + c[3]*w3;
    p += __shfl_xor(p, 16);
    p += __shfl_xor(p, 32);
    if (ft == hi)     outv0 += p;
    if (ft == hi + 4) outv1 += p;
  }
  size_t ob = (size_t)atom*FDIM;
  out[ob + lane]      += outv0;
  out[ob + 64 + lane] += outv1;
}

// ---------------- kernel p: env + j-sum -> all_p rows (bf16) -------------------
__global__ __launch_bounds__(256) void k_p(
    const float* __restrict__ gp, const int* __restrict__ nbr,
    char* __restrict__ ws)
{
  __shared__ alignas(16) char sm[4*(NJ*FPAD)];
  const int tid = threadIdx.x, lane = tid & 63;
  const int wid = __builtin_amdgcn_readfirstlane(tid >> 6);
  const int lo = lane & 15, hi = lane >> 4;
  const bool jvalid = lo < NJ;
  const int jc = jvalid ? lo : NJ-1;
  char* feaL = sm + wid*(NJ*FPAD);
  const unsigned short* feaP = (const unsigned short*)(ws + FEA_OFF) + FEA_ELEMS;
  unsigned short* allp = (unsigned short*)(ws + ALLP_OFF);
  const f32x4 z4 = {0.f,0.f,0.f,0.f};

  const int atom = (int)blockIdx.x*4 + wid;
  int nb = 0;
  if (lane < NJ) nb = nbr[(size_t)atom*NJ + lane];

  const float* gpp = gp + (size_t)atom*1152 + (jc*96 + hi*24);
  float pr[24];
  #pragma unroll
  for (int q = 0; q < 6; ++q){
    f32x4 v = *(const f32x4*)(gpp + q*4);
    #pragma unroll
    for (int c2 = 0; c2 < 4; ++c2) pr[q*4+c2] = v[c2];
  }
  stage_fea(feaL, feaP, nb, lane);

  short8 AfP[3];
  #pragma unroll
  for (int a = 0; a < 3; ++a)
    AfP[a] = frag4(pack_bf2(pr[0+a],pr[3+a]),   pack_bf2(pr[6+a],pr[9+a]),
                   pack_bf2(pr[12+a],pr[15+a]), pack_bf2(pr[18+a],pr[21+a]), jvalid);
  short8 Bg[8];
  #pragma unroll
  for (int ft = 0; ft < 8; ++ft)
    Bg[ft] = *(const short8*)(ws + GFRAG_OFF + 8192 + (size_t)((ft*64 + lane)*16));

  int rowoff[4];
  #pragma unroll
  for (int r = 0; r < 4; ++r){
    int j = hi*4 + r; if (j > NJ-1) j = NJ-1;
    rowoff[r] = j*FPAD;
  }

  lds_fence();
  #pragma unroll
  for (int ft = 0; ft < 8; ++ft){
    int fo = (ft*16 + lo)*2;
    float w0 = b2f(*(const unsigned short*)(feaL + rowoff[0] + fo));
    float w1 = b2f(*(const unsigned short*)(feaL + rowoff[1] + fo));
    float w2 = b2f(*(const unsigned short*)(feaL + rowoff[2] + fo));
    float w3 = b2f(*(const unsigned short*)(feaL + rowoff[3] + fo));
    #pragma unroll
    for (int a = 0; a < 3; ++a){
      f32x4 c = __builtin_amdgcn_mfma_f32_16x16x32_bf16(AfP[a], Bg[ft], z4, 0, 0, 0);
      float p = c[0]*w0 + c[1]*w1 + c[2]*w2 + c[3]*w3;
      p += __shfl_xor(p, 16);
      p += __shfl_xor(p, 32);
      if (lane < 16)
        allp[(size_t)(atom*3 + a)*FDIM + ft*16 + lane] = f2b(p);
    }
  }
}

// ---------------- kernel d: env + j-sum -> all_d rows (bf16) -------------------
__global__ __launch_bounds__(256) void k_d(
    const float* __restrict__ gd, const int* __restrict__ nbr,
    char* __restrict__ ws)
{
  __shared__ alignas(16) char sm[4*(NJ*FPAD)];
  const int tid = threadIdx.x, lane = tid & 63;
  const int wid = __builtin_amdgcn_readfirstlane(tid >> 6);
  const int lo = lane & 15, hi = lane >> 4;
  const bool jvalid = lo < NJ;
  const int jc = jvalid ? lo : NJ-1;
  char* feaL = sm + wid*(NJ*FPAD);
  const unsigned short* feaD = (const unsigned short*)(ws + FEA_OFF) + 2*FEA_ELEMS;
  unsigned short* alld = (unsigned short*)(ws + ALLD_OFF);
  const char* gfd = ws + GFRAG_OFF + 16384;
  const f32x4 z4 = {0.f,0.f,0.f,0.f};

  const int atom = (int)blockIdx.x*4 + wid;
  int nb = 0;
  if (lane < NJ) nb = nbr[(size_t)atom*NJ + lane];

  const float* gdp = gd + (size_t)atom*1920 + (jc*160 + hi*40);
  float dr[40];
  #pragma unroll
  for (int q = 0; q < 10; ++q){
    f32x4 v = *(const f32x4*)(gdp + q*4);
    #pragma unroll
    for (int c2 = 0; c2 < 4; ++c2) dr[q*4+c2] = v[c2];
  }
  stage_fea(feaL, feaD, nb, lane);

  short8 AfD[5];
  #pragma unroll
  for (int a = 0; a < 5; ++a)
    AfD[a] = frag4(pack_bf2(dr[0+a],dr[5+a]),   pack_bf2(dr[10+a],dr[15+a]),
                   pack_bf2(dr[20+a],dr[25+a]), pack_bf2(dr[30+a],dr[35+a]), jvalid);

  int rowoff[4];
  #pragma unroll
  for (int r = 0; r < 4; ++r){
    int j = hi*4 + r; if (j > NJ-1) j = NJ-1;
    rowoff[r] = j*FPAD;
  }

  lds_fence();
  short8 Bcur = *(const short8*)(gfd + (size_t)(lane*16));   // ft=0
  #pragma unroll
  for (int ft = 0; ft < 8; ++ft){
    short8 Bn;
    if (ft < 7) Bn = *(const short8*)(gfd + (size_t)(((ft+1)*64 + lane)*16));
    int fo = (ft*16 + lo)*2;
    float w0 = b2f(*(const unsigned short*)(feaL + rowoff[0] + fo));
    float w1 = b2f(*(const unsigned short*)(feaL + rowoff[1] + fo));
    float w2 = b2f(*(const unsigned short*)(feaL + rowoff[2] + fo));
    float w3 = b2f(*(const unsigned short*)(feaL + rowoff[3] + fo));
    #pragma unroll
    for (int a = 0; a < 5; ++a){
      f32x4 c = __builtin_amdgcn_mfma_f32_16x16x32_bf16(AfD[a], Bcur, z4, 0, 0, 0);
      float p = c[0]*w0 + c[1]*w1 + c[2]*w2 + c[3]*w3;
      p += __shfl_xor(p, 16);
      p += __shfl_xor(p, 32);
      if (lane < 16)
        alld[(size_t)(atom*5 + a)*FDIM + ft*16 + lane] = f2b(p);
    }
    Bcur = Bn;
  }
}

// ---------------- kernel quad: batched v^T M v over stored rows ----------------
__global__ __launch_bounds__(256) void k_quad(char* __restrict__ ws)
{
  __shared__ alignas(16) char mB[32768];
  const int tid = threadIdx.x, lane = tid & 63;
  const int wid = __builtin_amdgcn_readfirstlane(tid >> 6);
  const int lo = lane & 15, hi = lane >> 4;
  const int mat = blockIdx.y;
  const f32x4* msrc = (const f32x4*)(ws + MFRAG_OFF + (size_t)mat*32768);
  #pragma unroll
  for (int it = 0; it < 8; ++it)
    *((f32x4*)mB + it*256 + tid) = msrc[it*256 + tid];
  __syncthreads();

  const char* rows = ws + (mat ? ALLD_OFF : ALLP_OFF);
  float* qdst = (float*)(ws + (mat ? QD_OFF : QP_OFF));
  const int ntiles = mat ? (N_ATOMS*5)/16 : (N_ATOMS*3)/16;   // 9375 / 5625
  const int nw = (int)gridDim.x*4;

  for (int t = (int)blockIdx.x*4 + wid; t < ntiles; t += nw){
    const int rowb = t*16;
    // A-frags: 16 rows x 128 bf16, frag k = feature dim
    short8 Aq[4];
    #pragma unroll
    for (int ks = 0; ks < 4; ++ks)
      Aq[ks] = *(const short8*)(rows + (size_t)(rowb + lo)*256 + ks*64 + hi*16);
    // V scalars (same rows, C-layout positions) — L2-hot
    unsigned short vv[8][4];
    #pragma unroll
    for (int ft = 0; ft < 8; ++ft)
      #pragma unroll
      for (int r = 0; r < 4; ++r)
        vv[ft][r] = *(const unsigned short*)(rows + (size_t)(rowb + hi*4 + r)*256 + (ft*16 + lo)*2);

    f32x4 acc[8];
    #pragma unroll
    for (int ft = 0; ft < 8; ++ft) acc[ft] = (f32x4){0.f,0.f,0.f,0.f};
    #pragma unroll
    for (int ks = 0; ks < 4; ++ks){
      #pragma unroll
      for (int ft = 0; ft < 8; ++ft){
        short8 B = *(const short8*)(mB + (size_t)(((ks*8 + ft)*64 + lane)*16));
        acc[ft] = __builtin_amdgcn_mfma_f32_16x16x32_bf16(Aq[ks], B, acc[ft], 0, 0, 0);
      }
    }
    float part[4] = {0.f,0.f,0.f,0.f};
    #pragma unroll
    for (int ft = 0; ft < 8; ++ft)
      #pragma unroll
      for (int r = 0; r < 4; ++r)
        part[r] += acc[ft][r] * b2f(vv[ft][r]);
    #pragma unroll
    for (int r = 0; r < 4; ++r){
      #pragma unroll
      for (int m = 1; m < 16; m <<= 1) part[r] += __shfl_xor(part[r], m);
    }
    if (lo == 0){
      #pragma unroll
      for (int r = 0; r < 4; ++r) qdst[rowb + hi*4 + r] = part[r];
    }
  }
}

// ---------------- kernel final: out += broadcast quad sums ---------------------
__global__ __launch_bounds__(256) void k_final(char* __restrict__ ws,
                                               float* __restrict__ out)
{
  const float* qp = (const float*)(ws + QP_OFF);
  const float* qd = (const float*)(ws + QD_OFF);
  int e = (int)blockIdx.x*256 + threadIdx.x;   // e < 3,840,000
  int i = e >> 7;
  float q = qp[i*3] + qp[i*3+1] + qp[i*3+2]
          + qd[i*5] + qd[i*5+1] + qd[i*5+2] + qd[i*5+3] + qd[i*5+4];
  out[e] += q;
}

// ---------------- launch -------------------------------------------------------
extern "C" void kernel_launch(void* const* d_in, const int* in_sizes, int n_in,
                              void* d_out, int out_size, void* d_ws, size_t ws_size,
                              hipStream_t stream)
{
  const float* atom_fea = (const float*)d_in[0];
  const int*   nbr      = (const int*)d_in[1];
  const float* gs = (const float*)d_in[2];
  const float* gp = (const float*)d_in[3];
  const float* gd = (const float*)d_in[4];
  const float* Gs = (const float*)d_in[5];
  const float* Gp = (const float*)d_in[6];
  const float* Gd = (const float*)d_in[7];
  const float* P1 = (const float*)d_in[8];
  const float* P2 = (const float*)d_in[9];
  const float* D1 = (const float*)d_in[10];
  const float* D2 = (const float*)d_in[11];

  Ptr8 w8;
  w8.p[0] = (const float*)d_in[12];  // c_wr
  w8.p[1] = (const float*)d_in[14];  // c_w1
  w8.p[2] = (const float*)d_in[16];  // s_wr
  w8.p[3] = (const float*)d_in[18];  // s_w1
  w8.p[4] = (const float*)d_in[20];  // p_wr
  w8.p[5] = (const float*)d_in[22];  // p_w1
  w8.p[6] = (const float*)d_in[24];  // d_wr
  w8.p[7] = (const float*)d_in[26];  // d_w1
  Ptr3 g3; g3.p[0] = Gs; g3.p[1] = Gp; g3.p[2] = Gd;
  Bias bs;
  bs.br[0] = (const float*)d_in[13]; bs.b1[0] = (const float*)d_in[15];
  bs.br[1] = (const float*)d_in[17]; bs.b1[1] = (const float*)d_in[19];
  bs.br[2] = (const float*)d_in[21]; bs.b1[2] = (const float*)d_in[23];
  bs.br[3] = (const float*)d_in[25]; bs.b1[3] = (const float*)d_in[27];

  char* ws = (char*)d_ws;
  float* out = (float*)d_out;

  k_prep  <<<27, 256, 0, stream>>>(P1, P2, D1, D2, w8, g3, ws);
  dim3 g1((N_ATOMS + 63)/64, 4);
  k_resmlp<<<g1, 256, 0, stream>>>(atom_fea, ws, bs, out);
  k_s     <<<N_ATOMS/4, 256, 0, stream>>>(gs, nbr, ws, out);
  k_p     <<<N_ATOMS/4, 256, 0, stream>>>(gp, nbr, ws);
  k_d     <<<N_ATOMS/4, 256, 0, stream>>>(gd, nbr, ws);
  dim3 gq(256, 2);
  k_quad  <<<gq, 256, 0, stream>>>(ws);
  k_final <<<15000, 256, 0, stream>>>(ws, out);
}

// Round 7
// 261.260 us; speedup vs baseline: 1.4769x; 1.0337x over previous
//
#include <hip/hip_runtime.h>

#define N_ATOMS 30000
#define NJ 12
#define FDIM 128

typedef __attribute__((ext_vector_type(8))) short short8;
typedef __attribute__((ext_vector_type(4))) float f32x4;

// ws layout (bytes)
#define WFRAG_OFF 0          // 8 mats * 32768 B (bf16 frag-linear)
#define GFRAG_OFF 262144     // 3 mats * 8192 B
#define MFRAG_OFF 286720     // 2 mats * 32768 B
#define FEA_OFF   483328     // 3 * 30000*128 bf16 (s,p,d fea)
#define FEA_ELEMS 3840000
#define ALLP_OFF  23523328   // 90000 rows * 128 bf16
#define ALLD_OFF  46563328   // 150000 rows * 128 bf16
#define QP_OFF    84963328   // 90000 f32
#define QD_OFF    85323328   // 150000 f32

__device__ __forceinline__ unsigned short f2b(float f){
  unsigned u = __builtin_bit_cast(unsigned, f);
  u = (u + 0x7fffu + ((u >> 16) & 1u)) >> 16;
  return (unsigned short)u;
}
__device__ __forceinline__ float b2f(unsigned short s){
  unsigned u = ((unsigned)s) << 16;
  return __builtin_bit_cast(float, u);
}
__device__ __forceinline__ unsigned pack_bf2(float a, float b){
  unsigned ua = __builtin_bit_cast(unsigned, a);
  unsigned ub = __builtin_bit_cast(unsigned, b);
  ua = (ua + 0x7fffu + ((ua >> 16) & 1u)) >> 16;
  ub = (ub + 0x7fffu + ((ub >> 16) & 1u)) & 0xffff0000u;
  return ua | ub;
}
__device__ __forceinline__ float silu_f(float x){ return x / (1.0f + __expf(-x)); }
__device__ __forceinline__ void lds_fence(){
  __builtin_amdgcn_sched_barrier(0);
  asm volatile("s_waitcnt lgkmcnt(0)" ::: "memory");
  __builtin_amdgcn_sched_barrier(0);
}
__device__ __forceinline__ short8 frag4(unsigned d0, unsigned d1, unsigned d2, unsigned d3, bool valid){
  if (!valid){ d0 = 0u; d1 = 0u; d2 = 0u; d3 = 0u; }
  uint4 u; u.x = d0; u.y = d1; u.z = d2; u.w = d3;
  return __builtin_bit_cast(short8, u);
}

struct Ptr8 { const float* p[8]; };
struct Ptr3 { const float* p[3]; };
struct Bias { const float* br[4]; const float* b1[4]; };

// ---------------- kernel 0: M=P1*P2^T / D1*D2^T (direct frag), W/G frag pack ---
__global__ __launch_bounds__(256) void k_prep(
    const float* __restrict__ P1, const float* __restrict__ P2,
    const float* __restrict__ D1, const float* __restrict__ D2,
    Ptr8 w8, Ptr3 g3, char* __restrict__ ws)
{
  int b = blockIdx.x, t = threadIdx.x;
  if (b < 16){
    int mat = b >> 3, rb = b & 7;
    const float* A = mat ? D1 : P1;
    const float* B = mat ? D2 : P2;
    unsigned short* dst = (unsigned short*)(ws + MFRAG_OFF) + (size_t)mat*16384;
    for (int it = 0; it < 8; ++it){
      int o = it*256 + t;
      int row = rb*16 + (o >> 7), col = o & 127;   // row = k, col = f'
      const float4* ar = (const float4*)(A + (size_t)row*128);
      const float4* br = (const float4*)(B + (size_t)col*128);
      float s = 0.f;
      #pragma unroll 8
      for (int q = 0; q < 32; ++q){
        float4 a = ar[q], c = br[q];
        s += a.x*c.x + a.y*c.y + a.z*c.z + a.w*c.w;
      }
      int ks = row >> 5, ft = col >> 4;
      int ln = (col & 15) | (((row >> 3) & 3) << 4);
      dst[(size_t)(((ks*8 + ft)*64 + ln)*8 + (row & 7))] = f2b(s);
    }
  } else if (b < 24){
    int mat = b - 16;
    const float* W = w8.p[mat];
    unsigned short* dst = (unsigned short*)(ws + WFRAG_OFF) + (size_t)mat*16384;
    for (int it = 0; it < 64; ++it){
      int idx = it*256 + t;
      int i = idx & 7, ln = (idx >> 3) & 63, ft = (idx >> 9) & 7, ks = idx >> 12;
      int f = ft*16 + (ln & 15);
      int k = ks*32 + ((ln >> 4) & 3)*8 + i;
      dst[idx] = f2b(W[(size_t)f*128 + k]);
    }
  } else {
    int mat = b - 24;
    const float* G = g3.p[mat];
    unsigned short* dst = (unsigned short*)(ws + GFRAG_OFF) + (size_t)mat*4096;
    for (int it = 0; it < 16; ++it){
      int idx = it*256 + t;
      int i = idx & 7, ln = (idx >> 3) & 63, ft = idx >> 9;
      int f = ft*16 + (ln & 15);
      int k = ((ln >> 4) & 3)*8 + i;
      dst[idx] = f2b(G[(size_t)f*32 + k]);
    }
  }
}

// ---------------- kernel 1: ResMLP, one channel per block.y --------------------
__global__ __launch_bounds__(256) void k_resmlp(
    const float* __restrict__ x, char* __restrict__ ws, Bias bs,
    float* __restrict__ out)
{
  __shared__ alignas(16) char sm[32768];
  const int tid = threadIdx.x, lane = tid & 63;
  const int wid = __builtin_amdgcn_readfirstlane(tid >> 6);
  const int lo = lane & 15, hi = lane >> 4;
  const int ch = blockIdx.y;
  const int rowbase = (int)blockIdx.x*64 + wid*16;
  char* xL = sm + wid*8192;
  char* hL = xL + 4096;

  #pragma unroll
  for (int it = 0; it < 8; ++it){
    int e4 = it*64 + lane;
    int row = e4 >> 5, k0 = (e4 & 31)*4;
    int grow = rowbase + row; if (grow >= N_ATOMS) grow = N_ATOMS-1;
    float4 v = *(const float4*)(x + (size_t)grow*FDIM + k0);
    uint2 u;
    u.x = pack_bf2(silu_f(v.x), silu_f(v.y));
    u.y = pack_bf2(silu_f(v.z), silu_f(v.w));
    int ks = k0 >> 5, h2 = (k0 >> 3) & 3, i0 = k0 & 7, lanep = row | (h2 << 4);
    *(uint2*)(xL + ks*1024 + lanep*16 + i0*2) = u;
  }
  lds_fence();
  short8 A[4];
  #pragma unroll
  for (int ks = 0; ks < 4; ++ks) A[ks] = *(const short8*)(xL + ks*1024 + lane*16);

  const char* wrp = ws + (size_t)(ch*2)*32768;
  const char* w1p = ws + (size_t)(ch*2 + 1)*32768;
  const float* brp = bs.br[ch];
  const float* b1p = bs.b1[ch];

  f32x4 acc[8];
  #pragma unroll
  for (int ft = 0; ft < 8; ++ft) acc[ft] = (f32x4){0.f,0.f,0.f,0.f};
  #pragma unroll
  for (int ks = 0; ks < 4; ++ks){
    #pragma unroll
    for (int ft = 0; ft < 8; ++ft){
      short8 B = *(const short8*)(wrp + (size_t)(((ks*8 + ft)*64 + lane)*16));
      acc[ft] = __builtin_amdgcn_mfma_f32_16x16x32_bf16(A[ks], B, acc[ft], 0, 0, 0);
    }
  }
  #pragma unroll
  for (int ft = 0; ft < 8; ++ft){
    int f = ft*16 + lo;
    float bias = brp[f];
    #pragma unroll
    for (int r = 0; r < 4; ++r){
      int grow = rowbase + hi*4 + r; if (grow >= N_ATOMS) grow = N_ATOMS-1;
      float h = acc[ft][r] + x[(size_t)grow*FDIM + f] + bias;
      float sh = silu_f(h);
      int ks2 = f >> 5, h2 = (f >> 3) & 3, i2 = f & 7, lanep = (hi*4 + r) | (h2 << 4);
      *(unsigned short*)(hL + ks2*1024 + lanep*16 + i2*2) = f2b(sh);
    }
  }
  lds_fence();
  short8 A2[4];
  #pragma unroll
  for (int ks = 0; ks < 4; ++ks) A2[ks] = *(const short8*)(hL + ks*1024 + lane*16);

  f32x4 acc2[8];
  #pragma unroll
  for (int ft = 0; ft < 8; ++ft) acc2[ft] = (f32x4){0.f,0.f,0.f,0.f};
  #pragma unroll
  for (int ks = 0; ks < 4; ++ks){
    #pragma unroll
    for (int ft = 0; ft < 8; ++ft){
      short8 B = *(const short8*)(w1p + (size_t)(((ks*8 + ft)*64 + lane)*16));
      acc2[ft] = __builtin_amdgcn_mfma_f32_16x16x32_bf16(A2[ks], B, acc2[ft], 0, 0, 0);
    }
  }
  if (ch == 0){
    #pragma unroll
    for (int ft = 0; ft < 8; ++ft){
      int f = ft*16 + lo;
      float bb = b1p[f];
      #pragma unroll
      for (int r = 0; r < 4; ++r){
        int grow = rowbase + hi*4 + r; if (grow >= N_ATOMS) grow = N_ATOMS-1;
        out[(size_t)grow*FDIM + f] = acc2[ft][r] + bb;   // dup tail rows: identical
      }
    }
  } else {
    unsigned short* fea = (unsigned short*)(ws + FEA_OFF) + (size_t)(ch-1)*FEA_ELEMS;
    #pragma unroll
    for (int ft = 0; ft < 8; ++ft){
      int f = ft*16 + lo;
      float bb = b1p[f];
      #pragma unroll
      for (int r = 0; r < 4; ++r){
        int grow = rowbase + hi*4 + r; if (grow >= N_ATOMS) grow = N_ATOMS-1;
        fea[(size_t)grow*FDIM + f] = f2b(acc2[ft][r] + bb);
      }
    }
  }
}

// ---------------- channel kernel helpers ---------------------------------------
#define FPAD 288   // fea row pitch in LDS: 72 words -> hi-groups on disjoint banks

__device__ __forceinline__ void stage_fea(char* buf, const unsigned short* fea,
                                          int nb, int lane)
{
  #pragma unroll
  for (int j = 0; j < NJ; ++j){
    int nj = __shfl(nb, j);
    unsigned v = *(const unsigned*)(fea + (size_t)nj*FDIM + lane*2);
    *(unsigned*)(buf + j*FPAD + lane*4) = v;
  }
}

// ---------------- s channel body -----------------------------------------------
__device__ __forceinline__ void body_s(
    const float* __restrict__ gs, const int* __restrict__ nbr,
    char* __restrict__ ws, float* __restrict__ out,
    char* feaL, int atom, int lane, int lo, int hi, int jc, bool jvalid)
{
  const unsigned short* feaS = (const unsigned short*)(ws + FEA_OFF);
  const f32x4 z4 = {0.f,0.f,0.f,0.f};
  int nb = 0;
  if (lane < NJ) nb = nbr[(size_t)atom*NJ + lane];

  const float* gsp = gs + (size_t)atom*384 + (jc*32 + hi*8);
  f32x4 v0 = *(const f32x4*)(gsp);
  f32x4 v1 = *(const f32x4*)(gsp + 4);

  stage_fea(feaL, feaS, nb, lane);

  short8 AfS = frag4(pack_bf2(v0[0],v0[1]), pack_bf2(v0[2],v0[3]),
                     pack_bf2(v1[0],v1[1]), pack_bf2(v1[2],v1[3]), jvalid);
  short8 Bg[8];
  #pragma unroll
  for (int ft = 0; ft < 8; ++ft)
    Bg[ft] = *(const short8*)(ws + GFRAG_OFF + (size_t)((ft*64 + lane)*16));

  int rowoff[4];
  #pragma unroll
  for (int r = 0; r < 4; ++r){
    int j = hi*4 + r; if (j > NJ-1) j = NJ-1;
    rowoff[r] = j*FPAD;
  }

  lds_fence();
  float outv0 = 0.f, outv1 = 0.f;
  #pragma unroll
  for (int ft = 0; ft < 8; ++ft){
    int fo = (ft*16 + lo)*2;
    float w0 = b2f(*(const unsigned short*)(feaL + rowoff[0] + fo));
    float w1 = b2f(*(const unsigned short*)(feaL + rowoff[1] + fo));
    float w2 = b2f(*(const unsigned short*)(feaL + rowoff[2] + fo));
    float w3 = b2f(*(const unsigned short*)(feaL + rowoff[3] + fo));
    f32x4 c = __builtin_amdgcn_mfma_f32_16x16x32_bf16(AfS, Bg[ft], z4, 0, 0, 0);
    float p = c[0]*w0 + c[1]*w1 + c[2]*w2 + c[3]*w3;
    p += __shfl_xor(p, 16);
    p += __shfl_xor(p, 32);
    if (ft == hi)     outv0 += p;
    if (ft == hi + 4) outv1 += p;
  }
  size_t ob = (size_t)atom*FDIM;
  out[ob + lane]      += outv0;
  out[ob + 64 + lane] += outv1;
}

// ---------------- p channel body -----------------------------------------------
__device__ __forceinline__ void body_p(
    const float* __restrict__ gp, const int* __restrict__ nbr,
    char* __restrict__ ws,
    char* feaL, int atom, int lane, int lo, int hi, int jc, bool jvalid)
{
  const unsigned short* feaP = (const unsigned short*)(ws + FEA_OFF) + FEA_ELEMS;
  unsigned short* allp = (unsigned short*)(ws + ALLP_OFF);
  const f32x4 z4 = {0.f,0.f,0.f,0.f};
  int nb = 0;
  if (lane < NJ) nb = nbr[(size_t)atom*NJ + lane];

  const float* gpp = gp + (size_t)atom*1152 + (jc*96 + hi*24);
  float pr[24];
  #pragma unroll
  for (int q = 0; q < 6; ++q){
    f32x4 v = *(const f32x4*)(gpp + q*4);
    #pragma unroll
    for (int c2 = 0; c2 < 4; ++c2) pr[q*4+c2] = v[c2];
  }
  stage_fea(feaL, feaP, nb, lane);

  short8 AfP[3];
  #pragma unroll
  for (int a = 0; a < 3; ++a)
    AfP[a] = frag4(pack_bf2(pr[0+a],pr[3+a]),   pack_bf2(pr[6+a],pr[9+a]),
                   pack_bf2(pr[12+a],pr[15+a]), pack_bf2(pr[18+a],pr[21+a]), jvalid);
  short8 Bg[8];
  #pragma unroll
  for (int ft = 0; ft < 8; ++ft)
    Bg[ft] = *(const short8*)(ws + GFRAG_OFF + 8192 + (size_t)((ft*64 + lane)*16));

  int rowoff[4];
  #pragma unroll
  for (int r = 0; r < 4; ++r){
    int j = hi*4 + r; if (j > NJ-1) j = NJ-1;
    rowoff[r] = j*FPAD;
  }

  lds_fence();
  #pragma unroll
  for (int ft = 0; ft < 8; ++ft){
    int fo = (ft*16 + lo)*2;
    float w0 = b2f(*(const unsigned short*)(feaL + rowoff[0] + fo));
    float w1 = b2f(*(const unsigned short*)(feaL + rowoff[1] + fo));
    float w2 = b2f(*(const unsigned short*)(feaL + rowoff[2] + fo));
    float w3 = b2f(*(const unsigned short*)(feaL + rowoff[3] + fo));
    #pragma unroll
    for (int a = 0; a < 3; ++a){
      f32x4 c = __builtin_amdgcn_mfma_f32_16x16x32_bf16(AfP[a], Bg[ft], z4, 0, 0, 0);
      float p = c[0]*w0 + c[1]*w1 + c[2]*w2 + c[3]*w3;
      p += __shfl_xor(p, 16);
      p += __shfl_xor(p, 32);
      if (lane < 16)
        allp[(size_t)(atom*3 + a)*FDIM + ft*16 + lane] = f2b(p);
    }
  }
}

// ---------------- d channel body -----------------------------------------------
__device__ __forceinline__ void body_d(
    const float* __restrict__ gd, const int* __restrict__ nbr,
    char* __restrict__ ws,
    char* feaL, int atom, int lane, int lo, int hi, int jc, bool jvalid)
{
  const unsigned short* feaD = (const unsigned short*)(ws + FEA_OFF) + 2*FEA_ELEMS;
  unsigned short* alld = (unsigned short*)(ws + ALLD_OFF);
  const char* gfd = ws + GFRAG_OFF + 16384;
  const f32x4 z4 = {0.f,0.f,0.f,0.f};
  int nb = 0;
  if (lane < NJ) nb = nbr[(size_t)atom*NJ + lane];

  const float* gdp = gd + (size_t)atom*1920 + (jc*160 + hi*40);
  float dr[40];
  #pragma unroll
  for (int q = 0; q < 10; ++q){
    f32x4 v = *(const f32x4*)(gdp + q*4);
    #pragma unroll
    for (int c2 = 0; c2 < 4; ++c2) dr[q*4+c2] = v[c2];
  }
  stage_fea(feaL, feaD, nb, lane);

  short8 AfD[5];
  #pragma unroll
  for (int a = 0; a < 5; ++a)
    AfD[a] = frag4(pack_bf2(dr[0+a],dr[5+a]),   pack_bf2(dr[10+a],dr[15+a]),
                   pack_bf2(dr[20+a],dr[25+a]), pack_bf2(dr[30+a],dr[35+a]), jvalid);

  int rowoff[4];
  #pragma unroll
  for (int r = 0; r < 4; ++r){
    int j = hi*4 + r; if (j > NJ-1) j = NJ-1;
    rowoff[r] = j*FPAD;
  }

  lds_fence();
  short8 Bcur = *(const short8*)(gfd + (size_t)(lane*16));   // ft=0
  #pragma unroll
  for (int ft = 0; ft < 8; ++ft){
    short8 Bn;
    if (ft < 7) Bn = *(const short8*)(gfd + (size_t)(((ft+1)*64 + lane)*16));
    int fo = (ft*16 + lo)*2;
    float w0 = b2f(*(const unsigned short*)(feaL + rowoff[0] + fo));
    float w1 = b2f(*(const unsigned short*)(feaL + rowoff[1] + fo));
    float w2 = b2f(*(const unsigned short*)(feaL + rowoff[2] + fo));
    float w3 = b2f(*(const unsigned short*)(feaL + rowoff[3] + fo));
    #pragma unroll
    for (int a = 0; a < 5; ++a){
      f32x4 c = __builtin_amdgcn_mfma_f32_16x16x32_bf16(AfD[a], Bcur, z4, 0, 0, 0);
      float p = c[0]*w0 + c[1]*w1 + c[2]*w2 + c[3]*w3;
      p += __shfl_xor(p, 16);
      p += __shfl_xor(p, 32);
      if (lane < 16)
        alld[(size_t)(atom*5 + a)*FDIM + ft*16 + lane] = f2b(p);
    }
    Bcur = Bn;
  }
}

// ---------------- fused channel kernel: blockIdx.y picks s/p/d -----------------
__global__ __launch_bounds__(256) void k_chan(
    const float* __restrict__ gs, const float* __restrict__ gp,
    const float* __restrict__ gd, const int* __restrict__ nbr,
    char* __restrict__ ws, float* __restrict__ out)
{
  __shared__ alignas(16) char sm[4*(NJ*FPAD)];
  const int tid = threadIdx.x, lane = tid & 63;
  const int wid = __builtin_amdgcn_readfirstlane(tid >> 6);
  const int lo = lane & 15, hi = lane >> 4;
  const bool jvalid = lo < NJ;
  const int jc = jvalid ? lo : NJ-1;
  char* feaL = sm + wid*(NJ*FPAD);
  const int atom = (int)blockIdx.x*4 + wid;
  const int ch = (int)blockIdx.y;

  if (ch == 0)      body_s(gs, nbr, ws, out, feaL, atom, lane, lo, hi, jc, jvalid);
  else if (ch == 1) body_p(gp, nbr, ws, feaL, atom, lane, lo, hi, jc, jvalid);
  else              body_d(gd, nbr, ws, feaL, atom, lane, lo, hi, jc, jvalid);
}

// ---------------- kernel quad: batched v^T M v over stored rows ----------------
__global__ __launch_bounds__(256) void k_quad(char* __restrict__ ws)
{
  __shared__ alignas(16) char mB[32768];
  const int tid = threadIdx.x, lane = tid & 63;
  const int wid = __builtin_amdgcn_readfirstlane(tid >> 6);
  const int lo = lane & 15, hi = lane >> 4;
  const int mat = blockIdx.y;
  const f32x4* msrc = (const f32x4*)(ws + MFRAG_OFF + (size_t)mat*32768);
  #pragma unroll
  for (int it = 0; it < 8; ++it)
    *((f32x4*)mB + it*256 + tid) = msrc[it*256 + tid];
  __syncthreads();

  const char* rows = ws + (mat ? ALLD_OFF : ALLP_OFF);
  float* qdst = (float*)(ws + (mat ? QD_OFF : QP_OFF));
  const int ntiles = mat ? (N_ATOMS*5)/16 : (N_ATOMS*3)/16;   // 9375 / 5625
  const int nw = (int)gridDim.x*4;

  for (int t = (int)blockIdx.x*4 + wid; t < ntiles; t += nw){
    const int rowb = t*16;
    short8 Aq[4];
    #pragma unroll
    for (int ks = 0; ks < 4; ++ks)
      Aq[ks] = *(const short8*)(rows + (size_t)(rowb + lo)*256 + ks*64 + hi*16);
    unsigned short vv[8][4];
    #pragma unroll
    for (int ft = 0; ft < 8; ++ft)
      #pragma unroll
      for (int r = 0; r < 4; ++r)
        vv[ft][r] = *(const unsigned short*)(rows + (size_t)(rowb + hi*4 + r)*256 + (ft*16 + lo)*2);

    f32x4 acc[8];
    #pragma unroll
    for (int ft = 0; ft < 8; ++ft) acc[ft] = (f32x4){0.f,0.f,0.f,0.f};
    #pragma unroll
    for (int ks = 0; ks < 4; ++ks){
      #pragma unroll
      for (int ft = 0; ft < 8; ++ft){
        short8 B = *(const short8*)(mB + (size_t)(((ks*8 + ft)*64 + lane)*16));
        acc[ft] = __builtin_amdgcn_mfma_f32_16x16x32_bf16(Aq[ks], B, acc[ft], 0, 0, 0);
      }
    }
    float part[4] = {0.f,0.f,0.f,0.f};
    #pragma unroll
    for (int ft = 0; ft < 8; ++ft)
      #pragma unroll
      for (int r = 0; r < 4; ++r)
        part[r] += acc[ft][r] * b2f(vv[ft][r]);
    #pragma unroll
    for (int r = 0; r < 4; ++r){
      #pragma unroll
      for (int m = 1; m < 16; m <<= 1) part[r] += __shfl_xor(part[r], m);
    }
    if (lo == 0){
      #pragma unroll
      for (int r = 0; r < 4; ++r) qdst[rowb + hi*4 + r] = part[r];
    }
  }
}

// ---------------- kernel final: out += broadcast quad sums ---------------------
__global__ __launch_bounds__(256) void k_final(char* __restrict__ ws,
                                               float* __restrict__ out)
{
  const float* qp = (const float*)(ws + QP_OFF);
  const float* qd = (const float*)(ws + QD_OFF);
  int e = (int)blockIdx.x*256 + threadIdx.x;   // e < 3,840,000
  int i = e >> 7;
  float q = qp[i*3] + qp[i*3+1] + qp[i*3+2]
          + qd[i*5] + qd[i*5+1] + qd[i*5+2] + qd[i*5+3] + qd[i*5+4];
  out[e] += q;
}

// ---------------- launch -------------------------------------------------------
extern "C" void kernel_launch(void* const* d_in, const int* in_sizes, int n_in,
                              void* d_out, int out_size, void* d_ws, size_t ws_size,
                              hipStream_t stream)
{
  const float* atom_fea = (const float*)d_in[0];
  const int*   nbr      = (const int*)d_in[1];
  const float* gs = (const float*)d_in[2];
  const float* gp = (const float*)d_in[3];
  const float* gd = (const float*)d_in[4];
  const float* Gs = (const float*)d_in[5];
  const float* Gp = (const float*)d_in[6];
  const float* Gd = (const float*)d_in[7];
  const float* P1 = (const float*)d_in[8];
  const float* P2 = (const float*)d_in[9];
  const float* D1 = (const float*)d_in[10];
  const float* D2 = (const float*)d_in[11];

  Ptr8 w8;
  w8.p[0] = (const float*)d_in[12];  // c_wr
  w8.p[1] = (const float*)d_in[14];  // c_w1
  w8.p[2] = (const float*)d_in[16];  // s_wr
  w8.p[3] = (const float*)d_in[18];  // s_w1
  w8.p[4] = (const float*)d_in[20];  // p_wr
  w8.p[5] = (const float*)d_in[22];  // p_w1
  w8.p[6] = (const float*)d_in[24];  // d_wr
  w8.p[7] = (const float*)d_in[26];  // d_w1
  Ptr3 g3; g3.p[0] = Gs; g3.p[1] = Gp; g3.p[2] = Gd;
  Bias bs;
  bs.br[0] = (const float*)d_in[13]; bs.b1[0] = (const float*)d_in[15];
  bs.br[1] = (const float*)d_in[17]; bs.b1[1] = (const float*)d_in[19];
  bs.br[2] = (const float*)d_in[21]; bs.b1[2] = (const float*)d_in[23];
  bs.br[3] = (const float*)d_in[25]; bs.b1[3] = (const float*)d_in[27];

  char* ws = (char*)d_ws;
  float* out = (float*)d_out;

  k_prep  <<<27, 256, 0, stream>>>(P1, P2, D1, D2, w8, g3, ws);
  dim3 g1((N_ATOMS + 63)/64, 4);
  k_resmlp<<<g1, 256, 0, stream>>>(atom_fea, ws, bs, out);
  dim3 gc(N_ATOMS/4, 3);
  k_chan  <<<gc, 256, 0, stream>>>(gs, gp, gd, nbr, ws, out);
  dim3 gq(256, 2);
  k_quad  <<<gq, 256, 0, stream>>>(ws);
  k_final <<<15000, 256, 0, stream>>>(ws, out);
}